// Round 1
// baseline (789.803 us; speedup 1.0000x reference)
//
#include <hip/hip_runtime.h>

// Problem constants
#define B_   16
#define C_   512
#define HW_  4096
#define M_   1024   // pooled positions (HW/4)

typedef __attribute__((ext_vector_type(8))) short bf16x8;   // 8 bf16 = 4 VGPR
typedef __attribute__((ext_vector_type(4))) float f32x4;

static __device__ __forceinline__ unsigned short f2bf(float f) {
    union { float f; unsigned u; } v; v.f = f;
    unsigned r = v.u + 0x7fffu + ((v.u >> 16) & 1u);  // RNE
    return (unsigned short)(r >> 16);
}
static __device__ __forceinline__ float bf2f(unsigned short h) {
    union { unsigned u; float f; } v; v.u = ((unsigned)h) << 16;
    return v.f;
}

// ---------------------------------------------------------------------------
// K00: convert weights to bf16.
// Wb rows: [0,64) theta_w, [64,128) phi_w, [128,384) g_w. oWb = o_w [512][256].
__global__ __launch_bounds__(256) void k_weights(
    const float* __restrict__ thw, const float* __restrict__ phw,
    const float* __restrict__ gw,  const float* __restrict__ ow,
    unsigned short* __restrict__ Wb, unsigned short* __restrict__ oWb) {
    int i = blockIdx.x * 256 + threadIdx.x;
    if (i < 32768)            Wb[i] = f2bf(thw[i]);
    else if (i < 65536)       Wb[i] = f2bf(phw[i - 32768]);
    else if (i < 196608)      Wb[i] = f2bf(gw[i - 65536]);
    i -= 196608;
    if (i >= 0 && i < 131072) oWb[i] = f2bf(ow[i]);
}

// ---------------------------------------------------------------------------
// K0: x [B][512][4096] fp32 -> xT [B][4096][512] bf16 (LDS 64x64 transpose)
__global__ __launch_bounds__(256) void k_transpose_x(
    const float* __restrict__ x, unsigned short* __restrict__ xT) {
    __shared__ float tile[64][65];
    int b = blockIdx.z, c0 = blockIdx.y * 64, hw0 = blockIdx.x * 64;
    const float* xb = x + ((size_t)b * C_ + c0) * HW_ + hw0;
    int t = threadIdx.x;
    int r = t >> 4, c4 = (t & 15) * 4;
#pragma unroll
    for (int k = 0; k < 4; k++) {
        int row = r + k * 16;
        float4 v = *reinterpret_cast<const float4*>(xb + (size_t)row * HW_ + c4);
        tile[row][c4 + 0] = v.x; tile[row][c4 + 1] = v.y;
        tile[row][c4 + 2] = v.z; tile[row][c4 + 3] = v.w;
    }
    __syncthreads();
    unsigned short* o = xT + ((size_t)b * HW_ + hw0) * C_ + c0;
#pragma unroll
    for (int k = 0; k < 4; k++) {
        int hwr = r + k * 16;
        ushort4 u;
        u.x = f2bf(tile[c4 + 0][hwr]); u.y = f2bf(tile[c4 + 1][hwr]);
        u.z = f2bf(tile[c4 + 2][hwr]); u.w = f2bf(tile[c4 + 3][hwr]);
        *reinterpret_cast<ushort4*>(o + (size_t)hwr * C_ + c4) = u;
    }
}

// ---------------------------------------------------------------------------
// K1: projection GEMM per batch: P[384][4096] = Wb[384][512] @ X[512][4096]
// mtile 0 (rows 0-63 = theta) stores transposed to theta_n [B][4096][64] bf16.
// Other mtiles store to P_all [B][384][4096] bf16 (rows 64..383 used).
__global__ __launch_bounds__(256) void k_proj(
    const unsigned short* __restrict__ xT, const unsigned short* __restrict__ Wb,
    unsigned short* __restrict__ P_all, unsigned short* __restrict__ theta_n) {
    int b = blockIdx.z, m0 = blockIdx.y * 64, hw0 = blockIdx.x * 128;
    int lane = threadIdx.x & 63, w = threadIdx.x >> 6;
    int l15 = lane & 15, q = lane >> 4;
    int row = m0 + w * 16 + l15;                 // A row (out channel)
    const unsigned short* Arow = Wb + (size_t)row * 512 + q * 8;
    const unsigned short* Bbase = xT + ((size_t)b * HW_ + hw0) * C_ + q * 8;

    f32x4 acc[8] = {};
    for (int ks = 0; ks < 16; ks++) {
        bf16x8 a = *(const bf16x8*)(Arow + ks * 32);
#pragma unroll
        for (int cf = 0; cf < 8; cf++) {
            bf16x8 bb = *(const bf16x8*)(Bbase + (size_t)(cf * 16 + l15) * C_ + ks * 32);
            acc[cf] = __builtin_amdgcn_mfma_f32_16x16x32_bf16(a, bb, acc[cf], 0, 0, 0);
        }
    }
    if (m0 == 0) {
        // theta: [b][hw][k], lane holds 4 consecutive k = w*16 + q*4 + j
#pragma unroll
        for (int cf = 0; cf < 8; cf++) {
            ushort4 u;
            u.x = f2bf(acc[cf][0]); u.y = f2bf(acc[cf][1]);
            u.z = f2bf(acc[cf][2]); u.w = f2bf(acc[cf][3]);
            int hw = hw0 + cf * 16 + l15;
            *reinterpret_cast<ushort4*>(theta_n + ((size_t)b * HW_ + hw) * 64 + w * 16 + q * 4) = u;
        }
    } else {
#pragma unroll
        for (int cf = 0; cf < 8; cf++)
#pragma unroll
            for (int j = 0; j < 4; j++) {
                int r = m0 + w * 16 + q * 4 + j;
                P_all[((size_t)b * 384 + r) * HW_ + hw0 + cf * 16 + l15] = f2bf(acc[cf][j]);
            }
    }
}

// ---------------------------------------------------------------------------
// K2a: phi pool 2x2 + transpose: P_all rows[64,128) [64][4096] -> phi_p [B][1024][64]
__global__ __launch_bounds__(256) void k_pool_phi(
    const unsigned short* __restrict__ P_all, unsigned short* __restrict__ phi_p) {
    int idx = blockIdx.x * 256 + threadIdx.x;     // 16384 total
    int b = idx >> 10, m = idx & 1023;
    int hw00 = (m >> 5) * 128 + (m & 31) * 2;
    const unsigned short* src = P_all + ((size_t)b * 384 + 64) * HW_;
    unsigned short* dst = phi_p + ((size_t)b * M_ + m) * 64;
    for (int k = 0; k < 64; k++) {
        const unsigned short* r = src + (size_t)k * HW_ + hw00;
        float v = fmaxf(fmaxf(bf2f(r[0]), bf2f(r[1])), fmaxf(bf2f(r[64]), bf2f(r[65])));
        dst[k] = f2bf(v);
    }
}

// K2b: g pool 2x2: P_all rows[128,384) -> g_p [B][272][1024]; row 256 = ones, 257..271 = 0
__global__ __launch_bounds__(256) void k_pool_g(
    const unsigned short* __restrict__ P_all, unsigned short* __restrict__ g_p) {
    int b = blockIdx.x, c = blockIdx.y;
    unsigned short* dst = g_p + ((size_t)b * 272 + c) * M_ + threadIdx.x * 4;
    if (c >= 256) {
        unsigned short val = (c == 256) ? (unsigned short)0x3F80u : (unsigned short)0;
        ushort4 u; u.x = val; u.y = val; u.z = val; u.w = val;
        *reinterpret_cast<ushort4*>(dst) = u;
        return;
    }
    const unsigned short* src = P_all + ((size_t)b * 384 + 128 + c) * HW_;
    ushort4 u;
    unsigned short tmp[4];
#pragma unroll
    for (int i = 0; i < 4; i++) {
        int m = threadIdx.x * 4 + i;
        int hw00 = (m >> 5) * 128 + (m & 31) * 2;
        const unsigned short* r = src + hw00;
        float v = fmaxf(fmaxf(bf2f(r[0]), bf2f(r[1])), fmaxf(bf2f(r[64]), bf2f(r[65])));
        tmp[i] = f2bf(v);
    }
    u.x = tmp[0]; u.y = tmp[1]; u.z = tmp[2]; u.w = tmp[3];
    *reinterpret_cast<ushort4*>(dst) = u;
}

// ---------------------------------------------------------------------------
// K3: fused attention + output projection + residual.
// Per block: batch b, 64 query rows (4 waves x 16 rows). No __syncthreads.
// S = theta @ phi (K=64), P = exp(S) (no max-sub; logits bounded), streamed
// O[n][c] += P @ g^T with ones-row giving denominator at c=256.
// Epilogue: o_in = O/denom -> LDS -> out[n][512] = o_in @ oW^T; out = gamma*o + x.
__global__ __launch_bounds__(256) void k_attn(
    const unsigned short* __restrict__ theta_n, const unsigned short* __restrict__ phi_p,
    const unsigned short* __restrict__ g_p, const unsigned short* __restrict__ oWb,
    const float* __restrict__ x, const float* __restrict__ gamma_p,
    float* __restrict__ out) {
    __shared__ unsigned short p_lds[4][16][88];    // per-wave P tile [16n][64m], pad 88
    __shared__ unsigned short oin_lds[4][16][264]; // per-wave o_in [16n][256c], pad 264

    int b = blockIdx.y, n0 = blockIdx.x * 64;
    int tid = threadIdx.x, w = tid >> 6, lane = tid & 63;
    int l15 = lane & 15, q = lane >> 4;
    int nw = n0 + w * 16;

    // theta A-fragments (held all kernel): rows nw+l15, k = ks*32 + q*8 + [0..8)
    const unsigned short* th = theta_n + ((size_t)b * HW_ + nw + l15) * 64 + q * 8;
    bf16x8 a0 = *(const bf16x8*)(th);
    bf16x8 a1 = *(const bf16x8*)(th + 32);

    const unsigned short* phib = phi_p + (size_t)b * M_ * 64;
    const unsigned short* gb   = g_p   + (size_t)b * 272 * M_;

    f32x4 acc[17] = {};  // 16 c-frags (c 0..255) + frag 16 = denominator column
    for (int mc = 0; mc < 16; mc++) {
        int m0 = mc * 64;
        // ---- S phase: S[16n][64m] in 4 fragments, exp -> bf16 -> per-wave LDS
#pragma unroll
        for (int f = 0; f < 4; f++) {
            const unsigned short* pc = phib + (size_t)(m0 + f * 16 + l15) * 64 + q * 8;
            bf16x8 b0 = *(const bf16x8*)(pc);
            bf16x8 b1 = *(const bf16x8*)(pc + 32);
            f32x4 s = {};
            s = __builtin_amdgcn_mfma_f32_16x16x32_bf16(a0, b0, s, 0, 0, 0);
            s = __builtin_amdgcn_mfma_f32_16x16x32_bf16(a1, b1, s, 0, 0, 0);
#pragma unroll
            for (int j = 0; j < 4; j++)
                p_lds[w][q * 4 + j][f * 16 + l15] = f2bf(__expf(s[j]));
        }
        // ---- P A-fragments from LDS (same-wave dep; compiler inserts lgkmcnt)
        bf16x8 p0 = *(const bf16x8*)&p_lds[w][l15][q * 8];
        bf16x8 p1 = *(const bf16x8*)&p_lds[w][l15][32 + q * 8];
        // ---- O phase: acc[cf] += P[16n][64m] @ g^T[64m][16c]
#pragma unroll
        for (int cf = 0; cf < 17; cf++) {
            const unsigned short* gc = gb + (size_t)(cf * 16 + l15) * M_ + m0 + q * 8;
            bf16x8 g0 = *(const bf16x8*)(gc);
            bf16x8 g1 = *(const bf16x8*)(gc + 32);
            acc[cf] = __builtin_amdgcn_mfma_f32_16x16x32_bf16(p0, g0, acc[cf], 0, 0, 0);
            acc[cf] = __builtin_amdgcn_mfma_f32_16x16x32_bf16(p1, g1, acc[cf], 0, 0, 0);
        }
    }

    // ---- epilogue: divide by denominator (frag 16, col offset 0 => lanes l15==0)
    float dinv[4];
#pragma unroll
    for (int j = 0; j < 4; j++) {
        float d = __shfl(acc[16][j], (lane & 48), 64);
        dinv[j] = 1.0f / d;
    }
#pragma unroll
    for (int cf = 0; cf < 16; cf++)
#pragma unroll
        for (int j = 0; j < 4; j++)
            oin_lds[w][q * 4 + j][cf * 16 + l15] = f2bf(acc[cf][j] * dinv[j]);

    float gam = *gamma_p;
    // ---- fused output projection: out[n][cout] = o_in[n][0..256) @ oW[cout][0..256)
    for (int half = 0; half < 2; half++) {
        f32x4 oacc[16] = {};
        for (int kst = 0; kst < 8; kst++) {
            bf16x8 pa = *(const bf16x8*)&oin_lds[w][l15][kst * 32 + q * 8];
#pragma unroll
            for (int cf = 0; cf < 16; cf++) {
                int cout = half * 256 + cf * 16 + l15;
                bf16x8 bw = *(const bf16x8*)(oWb + (size_t)cout * 256 + kst * 32 + q * 8);
                oacc[cf] = __builtin_amdgcn_mfma_f32_16x16x32_bf16(pa, bw, oacc[cf], 0, 0, 0);
            }
        }
#pragma unroll
        for (int cf = 0; cf < 16; cf++) {
            int cout = half * 256 + cf * 16 + l15;
            size_t base = ((size_t)b * C_ + cout) * HW_ + nw + q * 4;
            float4 xv = *reinterpret_cast<const float4*>(x + base);
            float4 o;
            o.x = gam * oacc[cf][0] + xv.x;
            o.y = gam * oacc[cf][1] + xv.y;
            o.z = gam * oacc[cf][2] + xv.z;
            o.w = gam * oacc[cf][3] + xv.w;
            *reinterpret_cast<float4*>(out + base) = o;
        }
    }
}

// ---------------------------------------------------------------------------
extern "C" void kernel_launch(void* const* d_in, const int* in_sizes, int n_in,
                              void* d_out, int out_size, void* d_ws, size_t ws_size,
                              hipStream_t stream) {
    const float* x     = (const float*)d_in[0];
    const float* thw   = (const float*)d_in[1];
    const float* phw   = (const float*)d_in[2];
    const float* gw    = (const float*)d_in[3];
    const float* ow    = (const float*)d_in[4];
    const float* gamma = (const float*)d_in[5];
    float* out = (float*)d_out;

    char* ws = (char*)d_ws;
    // workspace layout (bytes), all 256-aligned
    unsigned short* xT   = (unsigned short*)(ws + 0);          //  67,108,864
    unsigned short* Wb   = (unsigned short*)(ws + 67108864);   //     393,216
    unsigned short* oWb  = (unsigned short*)(ws + 67502080);   //     262,144
    unsigned short* Pall = (unsigned short*)(ws + 67764224);   //  50,331,648
    unsigned short* thn  = (unsigned short*)(ws + 118095872);  //   8,388,608
    unsigned short* phip = (unsigned short*)(ws + 126484480);  //   2,097,152
    unsigned short* gp   = (unsigned short*)(ws + 128581632);  //   8,912,896  (end 137,494,528)

    hipLaunchKernelGGL(k_weights, dim3(1280), dim3(256), 0, stream, thw, phw, gw, ow, Wb, oWb);
    hipLaunchKernelGGL(k_transpose_x, dim3(64, 8, 16), dim3(256), 0, stream, x, xT);
    hipLaunchKernelGGL(k_proj, dim3(32, 6, 16), dim3(256), 0, stream, xT, Wb, Pall, thn);
    hipLaunchKernelGGL(k_pool_phi, dim3(64), dim3(256), 0, stream, Pall, phip);
    hipLaunchKernelGGL(k_pool_g, dim3(16, 272), dim3(256), 0, stream, Pall, gp);
    hipLaunchKernelGGL(k_attn, dim3(64, 16), dim3(256), 0, stream, thn, phip, gp, oWb, x, gamma, out);
}

// Round 2
// 445.279 us; speedup vs baseline: 1.7737x; 1.7737x over previous
//
#include <hip/hip_runtime.h>

// Problem constants
#define B_   16
#define C_   512
#define HW_  4096
#define M_   1024   // pooled positions (HW/4)

typedef __attribute__((ext_vector_type(8))) short bf16x8;   // 8 bf16 = 4 VGPR
typedef __attribute__((ext_vector_type(4))) float f32x4;

static __device__ __forceinline__ unsigned short f2bf(float f) {
    union { float f; unsigned u; } v; v.f = f;
    unsigned r = v.u + 0x7fffu + ((v.u >> 16) & 1u);  // RNE
    return (unsigned short)(r >> 16);
}
static __device__ __forceinline__ float bf2f(unsigned short h) {
    union { unsigned u; float f; } v; v.u = ((unsigned)h) << 16;
    return v.f;
}
static __device__ __forceinline__ void gload_lds16(const void* g, void* l) {
    __builtin_amdgcn_global_load_lds(
        (const __attribute__((address_space(1))) unsigned int*)g,
        (__attribute__((address_space(3))) unsigned int*)l, 16, 0, 0);
}

// ---------------------------------------------------------------------------
// K00: convert weights to bf16.
// Wb rows: [0,64) theta_w, [64,128) phi_w, [128,384) g_w. oWb = o_w [512][256].
__global__ __launch_bounds__(256) void k_weights(
    const float* __restrict__ thw, const float* __restrict__ phw,
    const float* __restrict__ gw,  const float* __restrict__ ow,
    unsigned short* __restrict__ Wb, unsigned short* __restrict__ oWb) {
    int i = blockIdx.x * 256 + threadIdx.x;
    if (i < 32768)            Wb[i] = f2bf(thw[i]);
    else if (i < 65536)       Wb[i] = f2bf(phw[i - 32768]);
    else if (i < 196608)      Wb[i] = f2bf(gw[i - 65536]);
    i -= 196608;
    if (i >= 0 && i < 131072) oWb[i] = f2bf(ow[i]);
}

// ---------------------------------------------------------------------------
// K0: x [B][512][4096] fp32 -> xT [B][4096][512] bf16 (LDS 64x64 transpose)
__global__ __launch_bounds__(256) void k_transpose_x(
    const float* __restrict__ x, unsigned short* __restrict__ xT) {
    __shared__ float tile[64][65];
    int b = blockIdx.z, c0 = blockIdx.y * 64, hw0 = blockIdx.x * 64;
    const float* xb = x + ((size_t)b * C_ + c0) * HW_ + hw0;
    int t = threadIdx.x;
    int r = t >> 4, c4 = (t & 15) * 4;
#pragma unroll
    for (int k = 0; k < 4; k++) {
        int row = r + k * 16;
        float4 v = *reinterpret_cast<const float4*>(xb + (size_t)row * HW_ + c4);
        tile[row][c4 + 0] = v.x; tile[row][c4 + 1] = v.y;
        tile[row][c4 + 2] = v.z; tile[row][c4 + 3] = v.w;
    }
    __syncthreads();
    unsigned short* o = xT + ((size_t)b * HW_ + hw0) * C_ + c0;
#pragma unroll
    for (int k = 0; k < 4; k++) {
        int hwr = r + k * 16;
        ushort4 u;
        u.x = f2bf(tile[c4 + 0][hwr]); u.y = f2bf(tile[c4 + 1][hwr]);
        u.z = f2bf(tile[c4 + 2][hwr]); u.w = f2bf(tile[c4 + 3][hwr]);
        *reinterpret_cast<ushort4*>(o + (size_t)hwr * C_ + c4) = u;
    }
}

// ---------------------------------------------------------------------------
// K1: projection GEMM per batch: P[384][4096] = Wb[384][512] @ X[512][4096]
// mtile 0 (rows 0-63 = theta) stores transposed to theta_n [B][4096][64] bf16.
// Other mtiles store to P_all [B][384][4096] bf16 (rows 64..383 used).
__global__ __launch_bounds__(256) void k_proj(
    const unsigned short* __restrict__ xT, const unsigned short* __restrict__ Wb,
    unsigned short* __restrict__ P_all, unsigned short* __restrict__ theta_n) {
    int b = blockIdx.z, m0 = blockIdx.y * 64, hw0 = blockIdx.x * 128;
    int lane = threadIdx.x & 63, w = threadIdx.x >> 6;
    int l15 = lane & 15, q = lane >> 4;
    int row = m0 + w * 16 + l15;                 // A row (out channel)
    const unsigned short* Arow = Wb + (size_t)row * 512 + q * 8;
    const unsigned short* Bbase = xT + ((size_t)b * HW_ + hw0) * C_ + q * 8;

    f32x4 acc[8] = {};
    for (int ks = 0; ks < 16; ks++) {
        bf16x8 a = *(const bf16x8*)(Arow + ks * 32);
#pragma unroll
        for (int cf = 0; cf < 8; cf++) {
            bf16x8 bb = *(const bf16x8*)(Bbase + (size_t)(cf * 16 + l15) * C_ + ks * 32);
            acc[cf] = __builtin_amdgcn_mfma_f32_16x16x32_bf16(a, bb, acc[cf], 0, 0, 0);
        }
    }
    if (m0 == 0) {
        // theta: [b][hw][k], lane holds 4 consecutive k = w*16 + q*4 + j
#pragma unroll
        for (int cf = 0; cf < 8; cf++) {
            ushort4 u;
            u.x = f2bf(acc[cf][0]); u.y = f2bf(acc[cf][1]);
            u.z = f2bf(acc[cf][2]); u.w = f2bf(acc[cf][3]);
            int hw = hw0 + cf * 16 + l15;
            *reinterpret_cast<ushort4*>(theta_n + ((size_t)b * HW_ + hw) * 64 + w * 16 + q * 4) = u;
        }
    } else {
#pragma unroll
        for (int cf = 0; cf < 8; cf++)
#pragma unroll
            for (int j = 0; j < 4; j++) {
                int r = m0 + w * 16 + q * 4 + j;
                P_all[((size_t)b * 384 + r) * HW_ + hw0 + cf * 16 + l15] = f2bf(acc[cf][j]);
            }
    }
}

// ---------------------------------------------------------------------------
// K2a: phi pool 2x2 + transpose: P_all rows[64,128) [64][4096] -> phi_p [B][1024][64]
__global__ __launch_bounds__(256) void k_pool_phi(
    const unsigned short* __restrict__ P_all, unsigned short* __restrict__ phi_p) {
    int idx = blockIdx.x * 256 + threadIdx.x;     // 65536 total: (b, m, kg)
    int b = idx >> 12, m = (idx >> 2) & 1023, kg = idx & 3;
    int hw00 = (m >> 5) * 128 + (m & 31) * 2;
    const unsigned short* src = P_all + ((size_t)b * 384 + 64) * HW_;
    unsigned short* dst = phi_p + ((size_t)b * M_ + m) * 64;
    for (int k = kg * 16; k < kg * 16 + 16; k++) {
        const unsigned short* r = src + (size_t)k * HW_ + hw00;
        float v = fmaxf(fmaxf(bf2f(r[0]), bf2f(r[1])), fmaxf(bf2f(r[64]), bf2f(r[65])));
        dst[k] = f2bf(v);
    }
}

// K2b: g pool 2x2: P_all rows[128,384) -> g_p [B][272][1024]; row 256 = ones, 257..271 = 0
__global__ __launch_bounds__(256) void k_pool_g(
    const unsigned short* __restrict__ P_all, unsigned short* __restrict__ g_p) {
    int b = blockIdx.x, c = blockIdx.y;
    unsigned short* dst = g_p + ((size_t)b * 272 + c) * M_ + threadIdx.x * 4;
    if (c >= 256) {
        unsigned short val = (c == 256) ? (unsigned short)0x3F80u : (unsigned short)0;
        ushort4 u; u.x = val; u.y = val; u.z = val; u.w = val;
        *reinterpret_cast<ushort4*>(dst) = u;
        return;
    }
    const unsigned short* src = P_all + ((size_t)b * 384 + 128 + c) * HW_;
    ushort4 u;
    unsigned short tmp[4];
#pragma unroll
    for (int i = 0; i < 4; i++) {
        int m = threadIdx.x * 4 + i;
        int hw00 = (m >> 5) * 128 + (m & 31) * 2;
        const unsigned short* r = src + hw00;
        float v = fmaxf(fmaxf(bf2f(r[0]), bf2f(r[1])), fmaxf(bf2f(r[64]), bf2f(r[65])));
        tmp[i] = f2bf(v);
    }
    u.x = tmp[0]; u.y = tmp[1]; u.z = tmp[2]; u.w = tmp[3];
    *reinterpret_cast<ushort4*>(dst) = u;
}

// ---------------------------------------------------------------------------
// K3: fused attention -> o_in [B][4096][256] bf16.
// Block = 512 threads (8 waves), 128 query rows (16/wave), batch b.
// Per m-chunk (64 cols): stage phi[64][64] + g[272][64] into LDS via
// global_load_lds w16, chunk-XOR-swizzled on the GLOBAL side (linear LDS dest),
// then S = theta@phi, P = exp(S) (no max-sub; logits bounded), O += P@g^T.
// Ones-row of g (row 256) accumulates the softmax denominator in acc[16].
__global__ __launch_bounds__(512, 4) void k_attn(
    const unsigned short* __restrict__ theta_n, const unsigned short* __restrict__ phi_p,
    const unsigned short* __restrict__ g_p, unsigned short* __restrict__ o_in) {
    __shared__ unsigned short phi_s[64 * 64];      //  8 KB, row=m, 8 chunks of 8 elem
    __shared__ unsigned short g_s[272 * 64];       // 34 KB, row=c
    __shared__ unsigned short p_lds[8][16][88];    // per-wave P tile [16n][64m]

    int b = blockIdx.y, n0 = blockIdx.x * 128;
    int tid = threadIdx.x, w = tid >> 6, lane = tid & 63;
    int l15 = lane & 15, q = lane >> 4;
    int nw = n0 + w * 16;

    // theta A-fragments (held all kernel): rows nw+l15, k = ks*32 + q*8 + [0..8)
    const unsigned short* th = theta_n + ((size_t)b * HW_ + nw + l15) * 64 + q * 8;
    bf16x8 a0 = *(const bf16x8*)(th);
    bf16x8 a1 = *(const bf16x8*)(th + 32);

    const unsigned short* phib = phi_p + (size_t)b * M_ * 64;
    const unsigned short* gb   = g_p   + (size_t)b * 272 * M_;

    int sw = l15 & 7;  // read-side XOR (row & 7 == l15 & 7 for all our rows)

    f32x4 acc[17] = {};  // 16 c-frags (c 0..255) + frag 16 = denominator column
    for (int mc = 0; mc < 16; mc++) {
        int m0 = mc * 64;
        __syncthreads();   // prior chunk's LDS reads complete before overwrite
        // ---- stage phi chunk: 8KB contiguous; 1 wave-issue per wave
        {
            int p = tid;                    // = w*64 + lane
            int row = p >> 3, ch = (p & 7) ^ (row & 7);
            gload_lds16(phib + (size_t)(m0 + row) * 64 + ch * 8, &phi_s[w * 512]);
        }
        // ---- stage g chunk: 34 segments of 1KB (8 rows each)
#pragma unroll
        for (int it = 0; it < 5; it++) {
            int s = w + it * 8;
            if (s < 34) {
                int row = s * 8 + (lane >> 3);
                int ch = (lane & 7) ^ (row & 7);
                gload_lds16(gb + (size_t)row * M_ + m0 + ch * 8, &g_s[s * 512]);
            }
        }
        __syncthreads();   // vmcnt(0) drain + barrier

        // ---- S phase: S[16n][64m] in 4 fragments, exp -> bf16 -> per-wave LDS
#pragma unroll
        for (int f = 0; f < 4; f++) {
            const unsigned short* pr = &phi_s[(f * 16 + l15) * 64];
            bf16x8 b0 = *(const bf16x8*)(pr + (q ^ sw) * 8);
            bf16x8 b1 = *(const bf16x8*)(pr + ((q + 4) ^ sw) * 8);
            f32x4 s = {};
            s = __builtin_amdgcn_mfma_f32_16x16x32_bf16(a0, b0, s, 0, 0, 0);
            s = __builtin_amdgcn_mfma_f32_16x16x32_bf16(a1, b1, s, 0, 0, 0);
#pragma unroll
            for (int j = 0; j < 4; j++)
                p_lds[w][q * 4 + j][f * 16 + l15] = f2bf(__expf(s[j]));
        }
        // ---- P A-fragments from LDS (same-wave dep; compiler inserts lgkmcnt)
        bf16x8 p0 = *(const bf16x8*)&p_lds[w][l15][q * 8];
        bf16x8 p1 = *(const bf16x8*)&p_lds[w][l15][32 + q * 8];
        // ---- O phase: acc[cf] += P[16n][64m] @ g^T[64m][16c]
#pragma unroll
        for (int cf = 0; cf < 17; cf++) {
            const unsigned short* gr = &g_s[(cf * 16 + l15) * 64];
            bf16x8 g0 = *(const bf16x8*)(gr + (q ^ sw) * 8);
            bf16x8 g1 = *(const bf16x8*)(gr + ((q + 4) ^ sw) * 8);
            acc[cf] = __builtin_amdgcn_mfma_f32_16x16x32_bf16(p0, g0, acc[cf], 0, 0, 0);
            acc[cf] = __builtin_amdgcn_mfma_f32_16x16x32_bf16(p1, g1, acc[cf], 0, 0, 0);
        }
    }

    // ---- epilogue: divide by denominator (frag 16, col 0 => lanes l15==0)
    float dinv[4];
#pragma unroll
    for (int j = 0; j < 4; j++) {
        float d = __shfl(acc[16][j], (lane & 48), 64);
        dinv[j] = 1.0f / d;
    }
#pragma unroll
    for (int cf = 0; cf < 16; cf++)
#pragma unroll
        for (int j = 0; j < 4; j++)
            o_in[((size_t)b * HW_ + nw + q * 4 + j) * 256 + cf * 16 + l15] =
                f2bf(acc[cf][j] * dinv[j]);
}

// ---------------------------------------------------------------------------
// K4: output projection + residual: out[b][cout][hw] = gamma * (o_in @ oW^T) + x
// Same structure as k_proj: A = oWb [512][256], B = o_in [b][n][256].
__global__ __launch_bounds__(256) void k_oproj(
    const unsigned short* __restrict__ o_in, const unsigned short* __restrict__ oWb,
    const float* __restrict__ x, const float* __restrict__ gamma_p,
    float* __restrict__ out) {
    int b = blockIdx.z, m0 = blockIdx.y * 64, hw0 = blockIdx.x * 128;
    int lane = threadIdx.x & 63, w = threadIdx.x >> 6;
    int l15 = lane & 15, q = lane >> 4;
    int row = m0 + w * 16 + l15;
    const unsigned short* Arow = oWb + (size_t)row * 256 + q * 8;
    const unsigned short* Bbase = o_in + ((size_t)b * HW_ + hw0) * 256 + q * 8;

    f32x4 acc[8] = {};
    for (int ks = 0; ks < 8; ks++) {
        bf16x8 a = *(const bf16x8*)(Arow + ks * 32);
#pragma unroll
        for (int cf = 0; cf < 8; cf++) {
            bf16x8 bb = *(const bf16x8*)(Bbase + (size_t)(cf * 16 + l15) * 256 + ks * 32);
            acc[cf] = __builtin_amdgcn_mfma_f32_16x16x32_bf16(a, bb, acc[cf], 0, 0, 0);
        }
    }
    float gam = *gamma_p;
#pragma unroll
    for (int cf = 0; cf < 8; cf++)
#pragma unroll
        for (int j = 0; j < 4; j++) {
            int r = m0 + w * 16 + q * 4 + j;
            size_t idx = ((size_t)b * C_ + r) * HW_ + hw0 + cf * 16 + l15;
            out[idx] = gam * acc[cf][j] + x[idx];
        }
}

// ---------------------------------------------------------------------------
extern "C" void kernel_launch(void* const* d_in, const int* in_sizes, int n_in,
                              void* d_out, int out_size, void* d_ws, size_t ws_size,
                              hipStream_t stream) {
    const float* x     = (const float*)d_in[0];
    const float* thw   = (const float*)d_in[1];
    const float* phw   = (const float*)d_in[2];
    const float* gw    = (const float*)d_in[3];
    const float* ow    = (const float*)d_in[4];
    const float* gamma = (const float*)d_in[5];
    float* out = (float*)d_out;

    char* ws = (char*)d_ws;
    // workspace layout (bytes), all 256-aligned
    unsigned short* xT   = (unsigned short*)(ws + 0);          //  67,108,864
    unsigned short* Wb   = (unsigned short*)(ws + 67108864);   //     393,216
    unsigned short* oWb  = (unsigned short*)(ws + 67502080);   //     262,144
    unsigned short* Pall = (unsigned short*)(ws + 67764224);   //  50,331,648
    unsigned short* thn  = (unsigned short*)(ws + 118095872);  //   8,388,608
    unsigned short* phip = (unsigned short*)(ws + 126484480);  //   2,097,152
    unsigned short* gp   = (unsigned short*)(ws + 128581632);  //   8,912,896  (end 137,494,528)
    // o_in [B][4096][256] bf16 = 33,554,432 B, overlaid on Pall (dead after pools)
    unsigned short* oin  = Pall;

    hipLaunchKernelGGL(k_weights, dim3(1280), dim3(256), 0, stream, thw, phw, gw, ow, Wb, oWb);
    hipLaunchKernelGGL(k_transpose_x, dim3(64, 8, 16), dim3(256), 0, stream, x, xT);
    hipLaunchKernelGGL(k_proj, dim3(32, 6, 16), dim3(256), 0, stream, xT, Wb, Pall, thn);
    hipLaunchKernelGGL(k_pool_phi, dim3(256), dim3(256), 0, stream, Pall, phip);
    hipLaunchKernelGGL(k_pool_g, dim3(16, 272), dim3(256), 0, stream, Pall, gp);
    hipLaunchKernelGGL(k_attn, dim3(32, 16), dim3(512), 0, stream, thn, phip, gp, oin);
    hipLaunchKernelGGL(k_oproj, dim3(32, 8, 16), dim3(256), 0, stream, oin, oWb, x, gamma, out);
}

// Round 3
// 233.731 us; speedup vs baseline: 3.3791x; 1.9051x over previous
//
#include <hip/hip_runtime.h>

// Problem constants
#define B_   16
#define C_   512
#define HW_  4096
#define M_   1024   // pooled positions (HW/4)

typedef __attribute__((ext_vector_type(8))) short bf16x8;   // 8 bf16 = 4 VGPR
typedef __attribute__((ext_vector_type(4))) float f32x4;

static __device__ __forceinline__ unsigned short f2bf(float f) {
    union { float f; unsigned u; } v; v.f = f;
    unsigned r = v.u + 0x7fffu + ((v.u >> 16) & 1u);  // RNE
    return (unsigned short)(r >> 16);
}
static __device__ __forceinline__ float bf2f(unsigned short h) {
    union { unsigned u; float f; } v; v.u = ((unsigned)h) << 16;
    return v.f;
}
static __device__ __forceinline__ void gload_lds16(const void* g, void* l) {
    __builtin_amdgcn_global_load_lds(
        (const __attribute__((address_space(1))) unsigned int*)g,
        (__attribute__((address_space(3))) unsigned int*)l, 16, 0, 0);
}

// ---------------------------------------------------------------------------
// K00: convert weights to bf16.
// Wb rows: [0,64) theta_w, [64,128) phi_w, [128,384) g_w. oWb = o_w [512][256].
__global__ __launch_bounds__(256) void k_weights(
    const float* __restrict__ thw, const float* __restrict__ phw,
    const float* __restrict__ gw,  const float* __restrict__ ow,
    unsigned short* __restrict__ Wb, unsigned short* __restrict__ oWb) {
    int i = blockIdx.x * 256 + threadIdx.x;
    if (i < 32768)            Wb[i] = f2bf(thw[i]);
    else if (i < 65536)       Wb[i] = f2bf(phw[i - 32768]);
    else if (i < 196608)      Wb[i] = f2bf(gw[i - 65536]);
    i -= 196608;
    if (i >= 0 && i < 131072) oWb[i] = f2bf(ow[i]);
}

// ---------------------------------------------------------------------------
// K0: x [B][512][4096] fp32 -> xT [B][4096][512] bf16 (LDS 64x64 transpose)
__global__ __launch_bounds__(256) void k_transpose_x(
    const float* __restrict__ x, unsigned short* __restrict__ xT) {
    __shared__ float tile[64][65];
    int b = blockIdx.z, c0 = blockIdx.y * 64, hw0 = blockIdx.x * 64;
    const float* xb = x + ((size_t)b * C_ + c0) * HW_ + hw0;
    int t = threadIdx.x;
    int r = t >> 4, c4 = (t & 15) * 4;
#pragma unroll
    for (int k = 0; k < 4; k++) {
        int row = r + k * 16;
        float4 v = *reinterpret_cast<const float4*>(xb + (size_t)row * HW_ + c4);
        tile[row][c4 + 0] = v.x; tile[row][c4 + 1] = v.y;
        tile[row][c4 + 2] = v.z; tile[row][c4 + 3] = v.w;
    }
    __syncthreads();
    unsigned short* o = xT + ((size_t)b * HW_ + hw0) * C_ + c0;
#pragma unroll
    for (int k = 0; k < 4; k++) {
        int hwr = r + k * 16;
        ushort4 u;
        u.x = f2bf(tile[c4 + 0][hwr]); u.y = f2bf(tile[c4 + 1][hwr]);
        u.z = f2bf(tile[c4 + 2][hwr]); u.w = f2bf(tile[c4 + 3][hwr]);
        *reinterpret_cast<ushort4*>(o + (size_t)hwr * C_ + c4) = u;
    }
}

// ---------------------------------------------------------------------------
// K1: projection GEMM per batch: P[384][4096] = Wb[384][512] @ xT_b^T.
// m97 structure: 128x128 tile, BK=64, 4 waves (2x2), LDS-staged A/B via
// global_load_lds w16 with chunk-XOR swizzle pre-applied on the GLOBAL side.
// m-tile 0 / wave-row 0 (rows 0-63 = theta) stores transposed to theta_n.
__global__ __launch_bounds__(256, 4) void k_proj(
    const unsigned short* __restrict__ xT, const unsigned short* __restrict__ Wb,
    unsigned short* __restrict__ P_all, unsigned short* __restrict__ theta_n) {
    __shared__ unsigned short As[128 * 64];   // 16 KB, row-major [row][64k]
    __shared__ unsigned short Bs[128 * 64];   // 16 KB

    int b = blockIdx.z, mt = blockIdx.y, hw0 = blockIdx.x * 128;
    int tid = threadIdx.x, w = tid >> 6, lane = tid & 63;
    int l15 = lane & 15, q = lane >> 4;
    int wr = w >> 1, wc = w & 1;

    const unsigned short* Ab = Wb + (size_t)(mt * 128) * 512;
    const unsigned short* Bb = xT + ((size_t)b * HW_ + hw0) * 512;
    int trow = tid >> 3, tch = tid & 7;

    f32x4 acc[4][4] = {};
    for (int ks = 0; ks < 8; ks++) {
        int k0 = ks * 64;
        if (ks) __syncthreads();
#pragma unroll
        for (int i = 0; i < 4; i++) {
            int row = i * 32 + trow;
            int ch = tch ^ (row & 7);
            gload_lds16(Ab + (size_t)row * 512 + k0 + ch * 8, &As[(i * 256 + w * 64) * 8]);
        }
#pragma unroll
        for (int i = 0; i < 4; i++) {
            int row = i * 32 + trow;
            int ch = tch ^ (row & 7);
            gload_lds16(Bb + (size_t)row * 512 + k0 + ch * 8, &Bs[(i * 256 + w * 64) * 8]);
        }
        __syncthreads();
#pragma unroll
        for (int kk = 0; kk < 2; kk++) {
            bf16x8 af[4], bfr[4];
#pragma unroll
            for (int mi = 0; mi < 4; mi++) {
                int row = wr * 64 + mi * 16 + l15;
                int ch = (kk * 4 + q) ^ (row & 7);
                af[mi] = *(const bf16x8*)&As[row * 64 + ch * 8];
            }
#pragma unroll
            for (int ni = 0; ni < 4; ni++) {
                int row = wc * 64 + ni * 16 + l15;
                int ch = (kk * 4 + q) ^ (row & 7);
                bfr[ni] = *(const bf16x8*)&Bs[row * 64 + ch * 8];
            }
#pragma unroll
            for (int mi = 0; mi < 4; mi++)
#pragma unroll
                for (int ni = 0; ni < 4; ni++)
                    acc[mi][ni] = __builtin_amdgcn_mfma_f32_16x16x32_bf16(
                        af[mi], bfr[ni], acc[mi][ni], 0, 0, 0);
        }
    }

    if (mt == 0 && wr == 0) {
        // theta rows 0..63: transposed store theta_n[b][hw][k], k=r, ushort4
#pragma unroll
        for (int mi = 0; mi < 4; mi++)
#pragma unroll
            for (int ni = 0; ni < 4; ni++) {
                ushort4 u;
                u.x = f2bf(acc[mi][ni][0]); u.y = f2bf(acc[mi][ni][1]);
                u.z = f2bf(acc[mi][ni][2]); u.w = f2bf(acc[mi][ni][3]);
                int hw = hw0 + wc * 64 + ni * 16 + l15;
                *reinterpret_cast<ushort4*>(
                    theta_n + ((size_t)b * HW_ + hw) * 64 + mi * 16 + q * 4) = u;
            }
    } else {
        int rbase = mt * 128 + wr * 64;
#pragma unroll
        for (int mi = 0; mi < 4; mi++)
#pragma unroll
            for (int ni = 0; ni < 4; ni++)
#pragma unroll
                for (int j = 0; j < 4; j++) {
                    int r = rbase + mi * 16 + q * 4 + j;
                    P_all[((size_t)b * 384 + r) * HW_ + hw0 + wc * 64 + ni * 16 + l15] =
                        f2bf(acc[mi][ni][j]);
                }
    }
}

// ---------------------------------------------------------------------------
// K2a: phi pool 2x2 + transpose: P_all rows[64,128) [64][4096] -> phi_p [B][1024][64]
__global__ __launch_bounds__(256) void k_pool_phi(
    const unsigned short* __restrict__ P_all, unsigned short* __restrict__ phi_p) {
    int idx = blockIdx.x * 256 + threadIdx.x;     // 65536 total: (b, m, kg)
    int b = idx >> 12, m = (idx >> 2) & 1023, kg = idx & 3;
    int hw00 = (m >> 5) * 128 + (m & 31) * 2;
    const unsigned short* src = P_all + ((size_t)b * 384 + 64) * HW_;
    unsigned short* dst = phi_p + ((size_t)b * M_ + m) * 64;
    for (int k = kg * 16; k < kg * 16 + 16; k++) {
        const unsigned short* r = src + (size_t)k * HW_ + hw00;
        float v = fmaxf(fmaxf(bf2f(r[0]), bf2f(r[1])), fmaxf(bf2f(r[64]), bf2f(r[65])));
        dst[k] = f2bf(v);
    }
}

// K2b: g pool 2x2: P_all rows[128,384) -> g_p [B][272][1024]; row 256 = ones, 257..271 = 0
__global__ __launch_bounds__(256) void k_pool_g(
    const unsigned short* __restrict__ P_all, unsigned short* __restrict__ g_p) {
    int b = blockIdx.x, c = blockIdx.y;
    unsigned short* dst = g_p + ((size_t)b * 272 + c) * M_ + threadIdx.x * 4;
    if (c >= 256) {
        unsigned short val = (c == 256) ? (unsigned short)0x3F80u : (unsigned short)0;
        ushort4 u; u.x = val; u.y = val; u.z = val; u.w = val;
        *reinterpret_cast<ushort4*>(dst) = u;
        return;
    }
    const unsigned short* src = P_all + ((size_t)b * 384 + 128 + c) * HW_;
    ushort4 u;
    unsigned short tmp[4];
#pragma unroll
    for (int i = 0; i < 4; i++) {
        int m = threadIdx.x * 4 + i;
        int hw00 = (m >> 5) * 128 + (m & 31) * 2;
        const unsigned short* r = src + hw00;
        float v = fmaxf(fmaxf(bf2f(r[0]), bf2f(r[1])), fmaxf(bf2f(r[64]), bf2f(r[65])));
        tmp[i] = f2bf(v);
    }
    u.x = tmp[0]; u.y = tmp[1]; u.z = tmp[2]; u.w = tmp[3];
    *reinterpret_cast<ushort4*>(dst) = u;
}

// ---------------------------------------------------------------------------
// K3: fused attention -> o_in [B][4096][256] bf16.
// Block = 512 threads (8 waves), 128 query rows (16/wave), batch b.
// Per m-chunk (64 cols): stage phi[64][64] + g[272][64] into LDS via
// global_load_lds w16, chunk-XOR-swizzled on the GLOBAL side (linear LDS dest),
// then S = theta@phi, P = exp(S) (no max-sub; logits bounded), O += P@g^T.
// Ones-row of g (row 256) accumulates the softmax denominator in acc[16].
__global__ __launch_bounds__(512, 4) void k_attn(
    const unsigned short* __restrict__ theta_n, const unsigned short* __restrict__ phi_p,
    const unsigned short* __restrict__ g_p, unsigned short* __restrict__ o_in) {
    __shared__ unsigned short phi_s[64 * 64];      //  8 KB, row=m, 8 chunks of 8 elem
    __shared__ unsigned short g_s[272 * 64];       // 34 KB, row=c
    __shared__ unsigned short p_lds[8][16][88];    // per-wave P tile [16n][64m]

    int b = blockIdx.y, n0 = blockIdx.x * 128;
    int tid = threadIdx.x, w = tid >> 6, lane = tid & 63;
    int l15 = lane & 15, q = lane >> 4;
    int nw = n0 + w * 16;

    // theta A-fragments (held all kernel): rows nw+l15, k = ks*32 + q*8 + [0..8)
    const unsigned short* th = theta_n + ((size_t)b * HW_ + nw + l15) * 64 + q * 8;
    bf16x8 a0 = *(const bf16x8*)(th);
    bf16x8 a1 = *(const bf16x8*)(th + 32);

    const unsigned short* phib = phi_p + (size_t)b * M_ * 64;
    const unsigned short* gb   = g_p   + (size_t)b * 272 * M_;

    int sw = l15 & 7;  // read-side XOR (row & 7 == l15 & 7 for all our rows)

    f32x4 acc[17] = {};  // 16 c-frags (c 0..255) + frag 16 = denominator column
    for (int mc = 0; mc < 16; mc++) {
        int m0 = mc * 64;
        __syncthreads();   // prior chunk's LDS reads complete before overwrite
        // ---- stage phi chunk: 8KB contiguous; 1 wave-issue per wave
        {
            int p = tid;                    // = w*64 + lane
            int row = p >> 3, ch = (p & 7) ^ (row & 7);
            gload_lds16(phib + (size_t)(m0 + row) * 64 + ch * 8, &phi_s[w * 512]);
        }
        // ---- stage g chunk: 34 segments of 1KB (8 rows each)
#pragma unroll
        for (int it = 0; it < 5; it++) {
            int s = w + it * 8;
            if (s < 34) {
                int row = s * 8 + (lane >> 3);
                int ch = (lane & 7) ^ (row & 7);
                gload_lds16(gb + (size_t)row * M_ + m0 + ch * 8, &g_s[s * 512]);
            }
        }
        __syncthreads();   // vmcnt(0) drain + barrier

        // ---- S phase: S[16n][64m] in 4 fragments, exp -> bf16 -> per-wave LDS
#pragma unroll
        for (int f = 0; f < 4; f++) {
            const unsigned short* pr = &phi_s[(f * 16 + l15) * 64];
            bf16x8 b0 = *(const bf16x8*)(pr + (q ^ sw) * 8);
            bf16x8 b1 = *(const bf16x8*)(pr + ((q + 4) ^ sw) * 8);
            f32x4 s = {};
            s = __builtin_amdgcn_mfma_f32_16x16x32_bf16(a0, b0, s, 0, 0, 0);
            s = __builtin_amdgcn_mfma_f32_16x16x32_bf16(a1, b1, s, 0, 0, 0);
#pragma unroll
            for (int j = 0; j < 4; j++)
                p_lds[w][q * 4 + j][f * 16 + l15] = f2bf(__expf(s[j]));
        }
        // ---- P A-fragments from LDS (same-wave dep; compiler inserts lgkmcnt)
        bf16x8 p0 = *(const bf16x8*)&p_lds[w][l15][q * 8];
        bf16x8 p1 = *(const bf16x8*)&p_lds[w][l15][32 + q * 8];
        // ---- O phase: acc[cf] += P[16n][64m] @ g^T[64m][16c]
#pragma unroll
        for (int cf = 0; cf < 17; cf++) {
            const unsigned short* gr = &g_s[(cf * 16 + l15) * 64];
            bf16x8 g0 = *(const bf16x8*)(gr + (q ^ sw) * 8);
            bf16x8 g1 = *(const bf16x8*)(gr + ((q + 4) ^ sw) * 8);
            acc[cf] = __builtin_amdgcn_mfma_f32_16x16x32_bf16(p0, g0, acc[cf], 0, 0, 0);
            acc[cf] = __builtin_amdgcn_mfma_f32_16x16x32_bf16(p1, g1, acc[cf], 0, 0, 0);
        }
    }

    // ---- epilogue: divide by denominator (frag 16, col 0 => lanes l15==0)
    float dinv[4];
#pragma unroll
    for (int j = 0; j < 4; j++) {
        float d = __shfl(acc[16][j], (lane & 48), 64);
        dinv[j] = 1.0f / d;
    }
#pragma unroll
    for (int cf = 0; cf < 16; cf++)
#pragma unroll
        for (int j = 0; j < 4; j++)
            o_in[((size_t)b * HW_ + nw + q * 4 + j) * 256 + cf * 16 + l15] =
                f2bf(acc[cf][j] * dinv[j]);
}

// ---------------------------------------------------------------------------
// K4: output projection + residual: out[b][cout][hw] = gamma * (o_in @ oW^T) + x
// Same m97 structure as k_proj: A = oWb [512][256], B = o_in [b][4096][256], K=256.
__global__ __launch_bounds__(256, 4) void k_oproj(
    const unsigned short* __restrict__ o_in, const unsigned short* __restrict__ oWb,
    const float* __restrict__ x, const float* __restrict__ gamma_p,
    float* __restrict__ out) {
    __shared__ unsigned short As[128 * 64];
    __shared__ unsigned short Bs[128 * 64];

    int b = blockIdx.z, mt = blockIdx.y, hw0 = blockIdx.x * 128;
    int tid = threadIdx.x, w = tid >> 6, lane = tid & 63;
    int l15 = lane & 15, q = lane >> 4;
    int wr = w >> 1, wc = w & 1;

    const unsigned short* Ab = oWb + (size_t)(mt * 128) * 256;
    const unsigned short* Bb = o_in + ((size_t)b * HW_ + hw0) * 256;
    int trow = tid >> 3, tch = tid & 7;

    f32x4 acc[4][4] = {};
    for (int ks = 0; ks < 4; ks++) {
        int k0 = ks * 64;
        if (ks) __syncthreads();
#pragma unroll
        for (int i = 0; i < 4; i++) {
            int row = i * 32 + trow;
            int ch = tch ^ (row & 7);
            gload_lds16(Ab + (size_t)row * 256 + k0 + ch * 8, &As[(i * 256 + w * 64) * 8]);
        }
#pragma unroll
        for (int i = 0; i < 4; i++) {
            int row = i * 32 + trow;
            int ch = tch ^ (row & 7);
            gload_lds16(Bb + (size_t)row * 256 + k0 + ch * 8, &Bs[(i * 256 + w * 64) * 8]);
        }
        __syncthreads();
#pragma unroll
        for (int kk = 0; kk < 2; kk++) {
            bf16x8 af[4], bfr[4];
#pragma unroll
            for (int mi = 0; mi < 4; mi++) {
                int row = wr * 64 + mi * 16 + l15;
                int ch = (kk * 4 + q) ^ (row & 7);
                af[mi] = *(const bf16x8*)&As[row * 64 + ch * 8];
            }
#pragma unroll
            for (int ni = 0; ni < 4; ni++) {
                int row = wc * 64 + ni * 16 + l15;
                int ch = (kk * 4 + q) ^ (row & 7);
                bfr[ni] = *(const bf16x8*)&Bs[row * 64 + ch * 8];
            }
#pragma unroll
            for (int mi = 0; mi < 4; mi++)
#pragma unroll
                for (int ni = 0; ni < 4; ni++)
                    acc[mi][ni] = __builtin_amdgcn_mfma_f32_16x16x32_bf16(
                        af[mi], bfr[ni], acc[mi][ni], 0, 0, 0);
        }
    }

    float gam = *gamma_p;
    int rbase = mt * 128 + wr * 64;
#pragma unroll
    for (int mi = 0; mi < 4; mi++)
#pragma unroll
        for (int ni = 0; ni < 4; ni++)
#pragma unroll
            for (int j = 0; j < 4; j++) {
                int r = rbase + mi * 16 + q * 4 + j;
                size_t idx = ((size_t)b * C_ + r) * HW_ + hw0 + wc * 64 + ni * 16 + l15;
                out[idx] = gam * acc[mi][ni][j] + x[idx];
            }
}

// ---------------------------------------------------------------------------
extern "C" void kernel_launch(void* const* d_in, const int* in_sizes, int n_in,
                              void* d_out, int out_size, void* d_ws, size_t ws_size,
                              hipStream_t stream) {
    const float* x     = (const float*)d_in[0];
    const float* thw   = (const float*)d_in[1];
    const float* phw   = (const float*)d_in[2];
    const float* gw    = (const float*)d_in[3];
    const float* ow    = (const float*)d_in[4];
    const float* gamma = (const float*)d_in[5];
    float* out = (float*)d_out;

    char* ws = (char*)d_ws;
    // workspace layout (bytes), all 256-aligned
    unsigned short* xT   = (unsigned short*)(ws + 0);          //  67,108,864
    unsigned short* Wb   = (unsigned short*)(ws + 67108864);   //     393,216
    unsigned short* oWb  = (unsigned short*)(ws + 67502080);   //     262,144
    unsigned short* Pall = (unsigned short*)(ws + 67764224);   //  50,331,648
    unsigned short* thn  = (unsigned short*)(ws + 118095872);  //   8,388,608
    unsigned short* phip = (unsigned short*)(ws + 126484480);  //   2,097,152
    unsigned short* gp   = (unsigned short*)(ws + 128581632);  //   8,912,896  (end 137,494,528)
    // o_in [B][4096][256] bf16 = 33,554,432 B, overlaid on Pall (dead after pools)
    unsigned short* oin  = Pall;

    hipLaunchKernelGGL(k_weights, dim3(1280), dim3(256), 0, stream, thw, phw, gw, ow, Wb, oWb);
    hipLaunchKernelGGL(k_transpose_x, dim3(64, 8, 16), dim3(256), 0, stream, x, xT);
    hipLaunchKernelGGL(k_proj, dim3(32, 3, 16), dim3(256), 0, stream, xT, Wb, Pall, thn);
    hipLaunchKernelGGL(k_pool_phi, dim3(256), dim3(256), 0, stream, Pall, phip);
    hipLaunchKernelGGL(k_pool_g, dim3(16, 272), dim3(256), 0, stream, Pall, gp);
    hipLaunchKernelGGL(k_attn, dim3(32, 16), dim3(512), 0, stream, thn, phip, gp, oin);
    hipLaunchKernelGGL(k_oproj, dim3(32, 4, 16), dim3(256), 0, stream, oin, oWb, x, gamma, out);
}

// Round 4
// 193.580 us; speedup vs baseline: 4.0800x; 1.2074x over previous
//
#include <hip/hip_runtime.h>

// Problem constants
#define B_   16
#define C_   512
#define HW_  4096
#define M_   1024   // pooled positions (HW/4)
#define TPAD 136    // LDS epilogue row pad (ushorts): 272 B = 16B-aligned rows

typedef __attribute__((ext_vector_type(8))) short bf16x8;   // 8 bf16 = 4 VGPR
typedef __attribute__((ext_vector_type(4))) float f32x4;

static __device__ __forceinline__ unsigned short f2bf(float f) {
    union { float f; unsigned u; } v; v.f = f;
    unsigned r = v.u + 0x7fffu + ((v.u >> 16) & 1u);  // RNE
    return (unsigned short)(r >> 16);
}
static __device__ __forceinline__ float bf2f(unsigned short h) {
    union { unsigned u; float f; } v; v.u = ((unsigned)h) << 16;
    return v.f;
}
static __device__ __forceinline__ void gload_lds16(const void* g, void* l) {
    __builtin_amdgcn_global_load_lds(
        (const __attribute__((address_space(1))) unsigned int*)g,
        (__attribute__((address_space(3))) unsigned int*)l, 16, 0, 0);
}

// ---------------------------------------------------------------------------
// K00: convert weights to bf16 + init g_p ones/zeros rows (256..271).
// Wb rows: [0,64) theta_w, [64,128) phi_w, [128,384) g_w. oWb = o_w [512][256].
__global__ __launch_bounds__(256) void k_weights(
    const float* __restrict__ thw, const float* __restrict__ phw,
    const float* __restrict__ gw,  const float* __restrict__ ow,
    unsigned short* __restrict__ Wb, unsigned short* __restrict__ oWb,
    unsigned short* __restrict__ g_p) {
    int i = blockIdx.x * 256 + threadIdx.x;
    if (i < 32768)        Wb[i] = f2bf(thw[i]);
    else if (i < 65536)   Wb[i] = f2bf(phw[i - 32768]);
    else if (i < 196608)  Wb[i] = f2bf(gw[i - 65536]);
    else if (i < 327680)  oWb[i - 196608] = f2bf(ow[i - 196608]);
    else if (i < 589824) {
        int i2 = i - 327680;          // [0, 262144): 16 b x 16 rows x 1024 m
        int b = i2 >> 14;
        int r = (i2 >> 10) & 15;      // row 256+r
        int m = i2 & 1023;
        g_p[((size_t)b * 272 + 256 + r) * M_ + m] =
            (r == 0) ? (unsigned short)0x3F80u : (unsigned short)0;
    }
}

// ---------------------------------------------------------------------------
// K0: x [B][512][4096] fp32 -> xT [B][4096][512] bf16 (LDS 64x64 transpose)
__global__ __launch_bounds__(256) void k_transpose_x(
    const float* __restrict__ x, unsigned short* __restrict__ xT) {
    __shared__ float tile[64][65];
    int b = blockIdx.z, c0 = blockIdx.y * 64, hw0 = blockIdx.x * 64;
    const float* xb = x + ((size_t)b * C_ + c0) * HW_ + hw0;
    int t = threadIdx.x;
    int r = t >> 4, c4 = (t & 15) * 4;
#pragma unroll
    for (int k = 0; k < 4; k++) {
        int row = r + k * 16;
        float4 v = *reinterpret_cast<const float4*>(xb + (size_t)row * HW_ + c4);
        tile[row][c4 + 0] = v.x; tile[row][c4 + 1] = v.y;
        tile[row][c4 + 2] = v.z; tile[row][c4 + 3] = v.w;
    }
    __syncthreads();
    unsigned short* o = xT + ((size_t)b * HW_ + hw0) * C_ + c0;
#pragma unroll
    for (int k = 0; k < 4; k++) {
        int hwr = r + k * 16;
        ushort4 u;
        u.x = f2bf(tile[c4 + 0][hwr]); u.y = f2bf(tile[c4 + 1][hwr]);
        u.z = f2bf(tile[c4 + 2][hwr]); u.w = f2bf(tile[c4 + 3][hwr]);
        *reinterpret_cast<ushort4*>(o + (size_t)hwr * C_ + c4) = u;
    }
}

// ---------------------------------------------------------------------------
// K1: projection GEMM per batch: P[384][4096] = Wb[384][512] @ xT_b^T, with
// FUSED epilogue: theta rows (mt0, 0-63) -> theta_n transposed; phi rows
// (mt0, 64-127) -> 2x2 maxpool -> phi_p transposed; g rows (mt1/2) -> 2x2
// maxpool -> g_p. Each block covers 2 full H-rows so pooling is intra-block.
// Tile restaged to LDS transposed [col][row] (pad 136) for coalesced output.
__global__ __launch_bounds__(256, 4) void k_proj(
    const unsigned short* __restrict__ xT, const unsigned short* __restrict__ Wb,
    unsigned short* __restrict__ theta_n, unsigned short* __restrict__ phi_p,
    unsigned short* __restrict__ g_p) {
    __shared__ unsigned short smem[128 * TPAD];   // 34,816 B; aliases As|Bs
    unsigned short* As = smem;                    // [0, 8192) ushorts
    unsigned short* Bs = smem + 8192;             // [8192, 16384)

    int b = blockIdx.z, mt = blockIdx.y, bx = blockIdx.x;
    int hw0 = bx * 128;
    int tid = threadIdx.x, w = tid >> 6, lane = tid & 63;
    int l15 = lane & 15, q = lane >> 4;
    int wr = w >> 1, wc = w & 1;

    const unsigned short* Ab = Wb + (size_t)(mt * 128) * 512;
    const unsigned short* Bb = xT + ((size_t)b * HW_ + hw0) * 512;
    int trow = tid >> 3, tch = tid & 7;

    f32x4 acc[4][4] = {};
    for (int ks = 0; ks < 8; ks++) {
        int k0 = ks * 64;
        if (ks) __syncthreads();
#pragma unroll
        for (int i = 0; i < 4; i++) {
            int row = i * 32 + trow;
            int ch = tch ^ (row & 7);
            gload_lds16(Ab + (size_t)row * 512 + k0 + ch * 8, &As[(i * 256 + w * 64) * 8]);
        }
#pragma unroll
        for (int i = 0; i < 4; i++) {
            int row = i * 32 + trow;
            int ch = tch ^ (row & 7);
            gload_lds16(Bb + (size_t)row * 512 + k0 + ch * 8, &Bs[(i * 256 + w * 64) * 8]);
        }
        __syncthreads();
#pragma unroll
        for (int kk = 0; kk < 2; kk++) {
            bf16x8 af[4], bfr[4];
#pragma unroll
            for (int mi = 0; mi < 4; mi++) {
                int row = wr * 64 + mi * 16 + l15;
                int ch = (kk * 4 + q) ^ (row & 7);
                af[mi] = *(const bf16x8*)&As[row * 64 + ch * 8];
            }
#pragma unroll
            for (int ni = 0; ni < 4; ni++) {
                int row = wc * 64 + ni * 16 + l15;
                int ch = (kk * 4 + q) ^ (row & 7);
                bfr[ni] = *(const bf16x8*)&Bs[row * 64 + ch * 8];
            }
#pragma unroll
            for (int mi = 0; mi < 4; mi++)
#pragma unroll
                for (int ni = 0; ni < 4; ni++)
                    acc[mi][ni] = __builtin_amdgcn_mfma_f32_16x16x32_bf16(
                        af[mi], bfr[ni], acc[mi][ni], 0, 0, 0);
        }
    }

    // ---- epilogue: restage tile TRANSPOSED: smem[col(hw_l)][row(ch_l)], pad 136
    __syncthreads();
#pragma unroll
    for (int mi = 0; mi < 4; mi++)
#pragma unroll
        for (int ni = 0; ni < 4; ni++) {
            int col = wc * 64 + ni * 16 + l15;
            int row = wr * 64 + mi * 16 + q * 4;
            ushort4 u;
            u.x = f2bf(acc[mi][ni][0]); u.y = f2bf(acc[mi][ni][1]);
            u.z = f2bf(acc[mi][ni][2]); u.w = f2bf(acc[mi][ni][3]);
            *reinterpret_cast<ushort4*>(&smem[col * TPAD + row]) = u;
        }
    __syncthreads();

    if (mt == 0) {
        // theta rows 0..63 -> theta_n[b][hw][k]: thread t = 1 hw x 32 k, 64 B copy
        int hw_l = tid >> 1, kh = (tid & 1) * 32;
        const unsigned short* srcp = &smem[hw_l * TPAD + kh];
        unsigned short* dstp = theta_n + ((size_t)b * HW_ + hw0 + hw_l) * 64 + kh;
#pragma unroll
        for (int i = 0; i < 4; i++)
            *reinterpret_cast<uint4*>(dstp + i * 8) =
                *reinterpret_cast<const uint4*>(srcp + i * 8);
        // phi rows 64..127 -> pool -> phi_p[b][m][64]: thread = 8 m x 1 pc
        int pc = tid & 63, mg = tid >> 6;
#pragma unroll
        for (int j = 0; j < 8; j++) {
            int m_l = mg * 8 + j, w_ = m_l * 2;
            float v0 = bf2f(smem[(w_)      * TPAD + 64 + pc]);
            float v1 = bf2f(smem[(w_ + 1)  * TPAD + 64 + pc]);
            float v2 = bf2f(smem[(64 + w_) * TPAD + 64 + pc]);
            float v3 = bf2f(smem[(65 + w_) * TPAD + 64 + pc]);
            float v = fmaxf(fmaxf(v0, v1), fmaxf(v2, v3));
            phi_p[((size_t)b * M_ + bx * 32 + m_l) * 64 + pc] = f2bf(v);
        }
    } else {
        // g rows -> pool -> g_p[b][gc][1024]: thread = 1 gc x 16 m (32 B store)
        int lr = tid & 127, half = tid >> 7;
        int gc = (mt - 1) * 128 + lr;
        unsigned short* dst = g_p + ((size_t)b * 272 + gc) * M_ + bx * 32 + half * 16;
        unsigned short tmp[16];
#pragma unroll
        for (int i = 0; i < 16; i++) {
            int w_ = (half * 16 + i) * 2;
            float v0 = bf2f(smem[(w_)      * TPAD + lr]);
            float v1 = bf2f(smem[(w_ + 1)  * TPAD + lr]);
            float v2 = bf2f(smem[(64 + w_) * TPAD + lr]);
            float v3 = bf2f(smem[(65 + w_) * TPAD + lr]);
            tmp[i] = f2bf(fmaxf(fmaxf(v0, v1), fmaxf(v2, v3)));
        }
#pragma unroll
        for (int i = 0; i < 4; i++)
            *reinterpret_cast<ushort4*>(dst + i * 4) =
                *reinterpret_cast<const ushort4*>(&tmp[i * 4]);
    }
}

// ---------------------------------------------------------------------------
// K3: fused attention -> o_in [B][4096][256] bf16.
// Block = 512 threads (8 waves), 128 query rows (16/wave), batch b.
// Per m-chunk (64 cols): stage phi[64][64] + g[272][64] into LDS via
// global_load_lds w16, chunk-XOR-swizzled on the GLOBAL side (linear LDS dest),
// then S = theta@phi, P = exp(S) (no max-sub; logits bounded), O += P@g^T.
// Ones-row of g (row 256) accumulates the softmax denominator in acc[16].
__global__ __launch_bounds__(512, 4) void k_attn(
    const unsigned short* __restrict__ theta_n, const unsigned short* __restrict__ phi_p,
    const unsigned short* __restrict__ g_p, unsigned short* __restrict__ o_in) {
    __shared__ unsigned short phi_s[64 * 64];      //  8 KB, row=m, 8 chunks of 8 elem
    __shared__ unsigned short g_s[272 * 64];       // 34 KB, row=c
    __shared__ unsigned short p_lds[8][16][88];    // per-wave P tile [16n][64m]

    int b = blockIdx.y, n0 = blockIdx.x * 128;
    int tid = threadIdx.x, w = tid >> 6, lane = tid & 63;
    int l15 = lane & 15, q = lane >> 4;
    int nw = n0 + w * 16;

    // theta A-fragments (held all kernel): rows nw+l15, k = ks*32 + q*8 + [0..8)
    const unsigned short* th = theta_n + ((size_t)b * HW_ + nw + l15) * 64 + q * 8;
    bf16x8 a0 = *(const bf16x8*)(th);
    bf16x8 a1 = *(const bf16x8*)(th + 32);

    const unsigned short* phib = phi_p + (size_t)b * M_ * 64;
    const unsigned short* gb   = g_p   + (size_t)b * 272 * M_;

    int sw = l15 & 7;  // read-side XOR (row & 7 == l15 & 7 for all our rows)

    f32x4 acc[17] = {};  // 16 c-frags (c 0..255) + frag 16 = denominator column
    for (int mc = 0; mc < 16; mc++) {
        int m0 = mc * 64;
        __syncthreads();   // prior chunk's LDS reads complete before overwrite
        // ---- stage phi chunk: 8KB contiguous; 1 wave-issue per wave
        {
            int p = tid;                    // = w*64 + lane
            int row = p >> 3, ch = (p & 7) ^ (row & 7);
            gload_lds16(phib + (size_t)(m0 + row) * 64 + ch * 8, &phi_s[w * 512]);
        }
        // ---- stage g chunk: 34 segments of 1KB (8 rows each)
#pragma unroll
        for (int it = 0; it < 5; it++) {
            int s = w + it * 8;
            if (s < 34) {
                int row = s * 8 + (lane >> 3);
                int ch = (lane & 7) ^ (row & 7);
                gload_lds16(gb + (size_t)row * M_ + m0 + ch * 8, &g_s[s * 512]);
            }
        }
        __syncthreads();   // vmcnt(0) drain + barrier

        // ---- S phase: S[16n][64m] in 4 fragments, exp -> bf16 -> per-wave LDS
#pragma unroll
        for (int f = 0; f < 4; f++) {
            const unsigned short* pr = &phi_s[(f * 16 + l15) * 64];
            bf16x8 b0 = *(const bf16x8*)(pr + (q ^ sw) * 8);
            bf16x8 b1 = *(const bf16x8*)(pr + ((q + 4) ^ sw) * 8);
            f32x4 s = {};
            s = __builtin_amdgcn_mfma_f32_16x16x32_bf16(a0, b0, s, 0, 0, 0);
            s = __builtin_amdgcn_mfma_f32_16x16x32_bf16(a1, b1, s, 0, 0, 0);
#pragma unroll
            for (int j = 0; j < 4; j++)
                p_lds[w][q * 4 + j][f * 16 + l15] = f2bf(__expf(s[j]));
        }
        // ---- P A-fragments from LDS (same-wave dep; compiler inserts lgkmcnt)
        bf16x8 p0 = *(const bf16x8*)&p_lds[w][l15][q * 8];
        bf16x8 p1 = *(const bf16x8*)&p_lds[w][l15][32 + q * 8];
        // ---- O phase: acc[cf] += P[16n][64m] @ g^T[64m][16c]
#pragma unroll
        for (int cf = 0; cf < 17; cf++) {
            const unsigned short* gr = &g_s[(cf * 16 + l15) * 64];
            bf16x8 g0 = *(const bf16x8*)(gr + (q ^ sw) * 8);
            bf16x8 g1 = *(const bf16x8*)(gr + ((q + 4) ^ sw) * 8);
            acc[cf] = __builtin_amdgcn_mfma_f32_16x16x32_bf16(p0, g0, acc[cf], 0, 0, 0);
            acc[cf] = __builtin_amdgcn_mfma_f32_16x16x32_bf16(p1, g1, acc[cf], 0, 0, 0);
        }
    }

    // ---- epilogue: divide by denominator (frag 16, col 0 => lanes l15==0)
    float dinv[4];
#pragma unroll
    for (int j = 0; j < 4; j++) {
        float d = __shfl(acc[16][j], (lane & 48), 64);
        dinv[j] = 1.0f / d;
    }
#pragma unroll
    for (int cf = 0; cf < 16; cf++)
#pragma unroll
        for (int j = 0; j < 4; j++)
            o_in[((size_t)b * HW_ + nw + q * 4 + j) * 256 + cf * 16 + l15] =
                f2bf(acc[cf][j] * dinv[j]);
}

// ---------------------------------------------------------------------------
// K4: output projection + residual: out[b][cout][hw] = gamma * (o_in @ oW^T) + x
// m97 mainloop + LDS-restaged epilogue: tile -> smem[row][col] (pad 136),
// then 32-lane groups write 512 B contiguous float4 rows (x reads coalesced).
__global__ __launch_bounds__(256, 4) void k_oproj(
    const unsigned short* __restrict__ o_in, const unsigned short* __restrict__ oWb,
    const float* __restrict__ x, const float* __restrict__ gamma_p,
    float* __restrict__ out) {
    __shared__ unsigned short smem[128 * TPAD];   // 34,816 B; aliases As|Bs
    unsigned short* As = smem;
    unsigned short* Bs = smem + 8192;

    int b = blockIdx.z, mt = blockIdx.y, hw0 = blockIdx.x * 128;
    int tid = threadIdx.x, w = tid >> 6, lane = tid & 63;
    int l15 = lane & 15, q = lane >> 4;
    int wr = w >> 1, wc = w & 1;

    const unsigned short* Ab = oWb + (size_t)(mt * 128) * 256;
    const unsigned short* Bb = o_in + ((size_t)b * HW_ + hw0) * 256;
    int trow = tid >> 3, tch = tid & 7;

    f32x4 acc[4][4] = {};
    for (int ks = 0; ks < 4; ks++) {
        int k0 = ks * 64;
        if (ks) __syncthreads();
#pragma unroll
        for (int i = 0; i < 4; i++) {
            int row = i * 32 + trow;
            int ch = tch ^ (row & 7);
            gload_lds16(Ab + (size_t)row * 256 + k0 + ch * 8, &As[(i * 256 + w * 64) * 8]);
        }
#pragma unroll
        for (int i = 0; i < 4; i++) {
            int row = i * 32 + trow;
            int ch = tch ^ (row & 7);
            gload_lds16(Bb + (size_t)row * 256 + k0 + ch * 8, &Bs[(i * 256 + w * 64) * 8]);
        }
        __syncthreads();
#pragma unroll
        for (int kk = 0; kk < 2; kk++) {
            bf16x8 af[4], bfr[4];
#pragma unroll
            for (int mi = 0; mi < 4; mi++) {
                int row = wr * 64 + mi * 16 + l15;
                int ch = (kk * 4 + q) ^ (row & 7);
                af[mi] = *(const bf16x8*)&As[row * 64 + ch * 8];
            }
#pragma unroll
            for (int ni = 0; ni < 4; ni++) {
                int row = wc * 64 + ni * 16 + l15;
                int ch = (kk * 4 + q) ^ (row & 7);
                bfr[ni] = *(const bf16x8*)&Bs[row * 64 + ch * 8];
            }
#pragma unroll
            for (int mi = 0; mi < 4; mi++)
#pragma unroll
                for (int ni = 0; ni < 4; ni++)
                    acc[mi][ni] = __builtin_amdgcn_mfma_f32_16x16x32_bf16(
                        af[mi], bfr[ni], acc[mi][ni], 0, 0, 0);
        }
    }

    // ---- epilogue: restage row-major smem[row(cout_l)][col(hw_l)], pad 136
    __syncthreads();
#pragma unroll
    for (int mi = 0; mi < 4; mi++)
#pragma unroll
        for (int ni = 0; ni < 4; ni++) {
            int col = wc * 64 + ni * 16 + l15;
            int rb = wr * 64 + mi * 16 + q * 4;
#pragma unroll
            for (int j = 0; j < 4; j++)
                smem[(rb + j) * TPAD + col] = f2bf(acc[mi][ni][j]);
        }
    __syncthreads();

    float gam = *gamma_p;
    int sub = tid >> 5, p32 = tid & 31;
#pragma unroll
    for (int p = 0; p < 16; p++) {
        int row = p * 8 + sub;
        ushort4 v = *reinterpret_cast<const ushort4*>(&smem[row * TPAD + p32 * 4]);
        size_t idx = ((size_t)b * C_ + mt * 128 + row) * HW_ + hw0 + p32 * 4;
        float4 xv = *reinterpret_cast<const float4*>(x + idx);
        float4 o;
        o.x = gam * bf2f(v.x) + xv.x;
        o.y = gam * bf2f(v.y) + xv.y;
        o.z = gam * bf2f(v.z) + xv.z;
        o.w = gam * bf2f(v.w) + xv.w;
        *reinterpret_cast<float4*>(out + idx) = o;
    }
}

// ---------------------------------------------------------------------------
extern "C" void kernel_launch(void* const* d_in, const int* in_sizes, int n_in,
                              void* d_out, int out_size, void* d_ws, size_t ws_size,
                              hipStream_t stream) {
    const float* x     = (const float*)d_in[0];
    const float* thw   = (const float*)d_in[1];
    const float* phw   = (const float*)d_in[2];
    const float* gw    = (const float*)d_in[3];
    const float* ow    = (const float*)d_in[4];
    const float* gamma = (const float*)d_in[5];
    float* out = (float*)d_out;

    char* ws = (char*)d_ws;
    // workspace layout (bytes), all 256-aligned
    unsigned short* xT   = (unsigned short*)(ws + 0);          //  67,108,864
    unsigned short* Wb   = (unsigned short*)(ws + 67108864);   //     393,216
    unsigned short* oWb  = (unsigned short*)(ws + 67502080);   //     262,144
    unsigned short* oin  = (unsigned short*)(ws + 67764224);   //  33,554,432
    unsigned short* thn  = (unsigned short*)(ws + 118095872);  //   8,388,608
    unsigned short* phip = (unsigned short*)(ws + 126484480);  //   2,097,152
    unsigned short* gp   = (unsigned short*)(ws + 128581632);  //   8,912,896  (end 137,494,528)

    hipLaunchKernelGGL(k_weights, dim3(2304), dim3(256), 0, stream, thw, phw, gw, ow, Wb, oWb, gp);
    hipLaunchKernelGGL(k_transpose_x, dim3(64, 8, 16), dim3(256), 0, stream, x, xT);
    hipLaunchKernelGGL(k_proj, dim3(32, 3, 16), dim3(256), 0, stream, xT, Wb, thn, phip, gp);
    hipLaunchKernelGGL(k_attn, dim3(32, 16), dim3(512), 0, stream, thn, phip, gp, oin);
    hipLaunchKernelGGL(k_oproj, dim3(32, 4, 16), dim3(256), 0, stream, oin, oWb, x, gamma, out);
}